// Round 4
// baseline (34042.844 us; speedup 1.0000x reference)
//
#include <hip/hip_runtime.h>
#include <stdint.h>

// LSTM, E=2048, B=2, T=2048, fp32 I/O. For t>=1 input==h, so
// gates = h @ (W_ih+W_hh)^T + (b_ih+b_hh). Wc lives UNPACKED FP32 IN
// REGISTERS: each lane holds its 128 weights in 128 VGPRs (no LDS weight
// traffic, no unpack VALU). 256 blocks (1/CU) x 512 threads, cooperative
// for co-residency only — ZERO barriers in the steady-state loop:
//  - each wave polls only its own 256-elem k-window from the global
//    tagged-chunk buffer (2048 chunks, [tag32|bf16 h0|bf16 h1]),
//  - stages h into its private hlds window (wave-lockstep + lgkmcnt),
//  - computes partials, publishes to LDS pls + per-wave LDS tag,
//  - every wave reduces its OWN element (wave w -> element e0+w) via
//    8-lane groups + shfl, keeps c in lane registers, fires its chunk.
// pls/ptag parity-double-buffered; chunk reuse is depth-2 safe because
// every block consumes ALL elements each step (transitive guarantee).

#define E 2048
#define NBLK 256
#define NTHR 512
#define SMEM_PROJ 131072

typedef unsigned short u16;
typedef uint32_t u32;
typedef unsigned long long u64;

__device__ __forceinline__ float lo16(u32 u){ return __uint_as_float(u << 16); }
__device__ __forceinline__ float hi16(u32 u){ return __uint_as_float(u & 0xffff0000u); }
__device__ __forceinline__ u16 f2bf(float f){
  u32 u = __float_as_uint(f);
  u32 r = u + 0x7fffu + ((u >> 16) & 1u);   // RNE
  return (u16)(r >> 16);
}
__device__ __forceinline__ float sigf(float x){ return 1.0f / (1.0f + __expf(-x)); }

__global__ void __launch_bounds__(NTHR, 2) lstm_kernel(
    const float* __restrict__ xin, const float* __restrict__ Wih,
    const float* __restrict__ Whh, const float* __restrict__ bih,
    const float* __restrict__ bhh, u64* __restrict__ chk,
    float* __restrict__ seqout)
{
  __shared__ float hlds[2 * E];        // h (or x) fp32 [2][2048] = 16 KB
  __shared__ float pls[2][1040];       // [parity][b*520 + wv*65 + kh*32 + row]
  __shared__ u32  ptag[2][8];          // per-wave partial tags

  const int tid  = threadIdx.x;
  const int blk  = blockIdx.x;
  const int e0   = blk << 3;           // block owns elements e0..e0+7
  const int lane = tid & 63;
  const int wv   = tid >> 6;           // wave 0..7; wave wv reduces element e0+wv
  const int r    = lane & 31;          // row within block (gate*8 + eoff)
  const int kh   = lane >> 5;          // k-half
  const int kbase = (wv << 8) + (kh << 7);          // 128-wide k window
  const int grow_r = ((r >> 3) << 11) + e0 + (r & 7);

  // ---- Wc into registers: wf[c][j] = (Wih+Whh)[grow_r][kbase + c*8 + j]
  float wf[16][8];
  {
    const float* pa = Wih + (size_t)grow_r * E + kbase;
    const float* pb = Whh + (size_t)grow_r * E + kbase;
    #pragma unroll
    for (int c = 0; c < 16; ++c){
      float4 a0 = *(const float4*)(pa + (c << 3));
      float4 a1 = *(const float4*)(pa + (c << 3) + 4);
      float4 b0 = *(const float4*)(pb + (c << 3));
      float4 b1 = *(const float4*)(pb + (c << 3) + 4);
      wf[c][0] = a0.x + b0.x; wf[c][1] = a0.y + b0.y;
      wf[c][2] = a0.z + b0.z; wf[c][3] = a0.w + b0.w;
      wf[c][4] = a1.x + b1.x; wf[c][5] = a1.y + b1.y;
      wf[c][6] = a1.z + b1.z; wf[c][7] = a1.w + b1.w;
    }
  }
  float bg[4];
  #pragma unroll
  for (int g = 0; g < 4; ++g)
    bg[g] = bih[(g << 11) + e0 + wv] + bhh[(g << 11) + e0 + wv];

  float c_reg = 0.0f;                  // real c in lanes 0,1 only

  for (int i = tid; i < 2 * E; i += NTHR) hlds[i] = xin[i];   // x for t=0
  if (tid < 16) ((u32*)ptag)[tid] = 0;
  __syncthreads();                     // the ONLY block barrier

  const int ebase = kbase + (r << 2);  // this lane stages elements ebase..+3

  for (int t = 0; t < 2048; ++t){
    const int p = t & 1;

    // ---- poll own window's h(t) chunks, stage to private hlds window ----
    if (t > 0){
      const u64* src = chk + (p << 11);
      const u32 want = (u32)t;
      u64 uu[4];
      #pragma unroll
      for (int k = 0; k < 4; ++k)
        uu[k] = __hip_atomic_load(&src[ebase + k],
                                  __ATOMIC_RELAXED, __HIP_MEMORY_SCOPE_AGENT);
      for (;;){
        bool ok = ((u32)(uu[0] >> 32) == want) && ((u32)(uu[1] >> 32) == want) &&
                  ((u32)(uu[2] >> 32) == want) && ((u32)(uu[3] >> 32) == want);
        if (ok) break;
        __builtin_amdgcn_s_sleep(1);
        #pragma unroll
        for (int k = 0; k < 4; ++k)
          if ((u32)(uu[k] >> 32) != want)
            uu[k] = __hip_atomic_load(&src[ebase + k],
                                      __ATOMIC_RELAXED, __HIP_MEMORY_SCOPE_AGENT);
      }
      float4 v0 = { lo16((u32)uu[0]), lo16((u32)uu[1]),
                    lo16((u32)uu[2]), lo16((u32)uu[3]) };
      float4 v1 = { hi16((u32)uu[0]), hi16((u32)uu[1]),
                    hi16((u32)uu[2]), hi16((u32)uu[3]) };
      *(float4*)(&hlds[ebase])     = v0;
      *(float4*)(&hlds[E + ebase]) = v1;
      __asm__ volatile("s_waitcnt lgkmcnt(0)" ::: "memory");  // wave-internal
    }

    // ---- partial dot: row grow_r over k window [kbase, kbase+128) ----
    float a0 = 0.0f, a1 = 0.0f;
    const float* hp0 = &hlds[kbase];
    const float* hp1 = &hlds[E + kbase];
    if (t == 0){                       // x @ W_ih^T, fp32 weights from global
      const float* ws = Wih + (size_t)grow_r * E + kbase;
      #pragma unroll
      for (int c = 0; c < 16; ++c){
        float4 w0 = *(const float4*)(ws + (c << 3));
        float4 w1 = *(const float4*)(ws + (c << 3) + 4);
        float4 x0 = *(const float4*)(hp0 + (c << 3));
        float4 x1 = *(const float4*)(hp0 + (c << 3) + 4);
        float4 y0 = *(const float4*)(hp1 + (c << 3));
        float4 y1 = *(const float4*)(hp1 + (c << 3) + 4);
        a0 = fmaf(w0.x,x0.x,a0); a0 = fmaf(w0.y,x0.y,a0);
        a0 = fmaf(w0.z,x0.z,a0); a0 = fmaf(w0.w,x0.w,a0);
        a0 = fmaf(w1.x,x1.x,a0); a0 = fmaf(w1.y,x1.y,a0);
        a0 = fmaf(w1.z,x1.z,a0); a0 = fmaf(w1.w,x1.w,a0);
        a1 = fmaf(w0.x,y0.x,a1); a1 = fmaf(w0.y,y0.y,a1);
        a1 = fmaf(w0.z,y0.z,a1); a1 = fmaf(w0.w,y0.w,a1);
        a1 = fmaf(w1.x,y1.x,a1); a1 = fmaf(w1.y,y1.y,a1);
        a1 = fmaf(w1.z,y1.z,a1); a1 = fmaf(w1.w,y1.w,a1);
      }
    } else {                           // h @ Wc^T, weights from registers
      #pragma unroll
      for (int c = 0; c < 16; ++c){
        float4 x0 = *(const float4*)(hp0 + (c << 3));
        float4 x1 = *(const float4*)(hp0 + (c << 3) + 4);
        float4 y0 = *(const float4*)(hp1 + (c << 3));
        float4 y1 = *(const float4*)(hp1 + (c << 3) + 4);
        a0 = fmaf(wf[c][0],x0.x,a0); a0 = fmaf(wf[c][1],x0.y,a0);
        a0 = fmaf(wf[c][2],x0.z,a0); a0 = fmaf(wf[c][3],x0.w,a0);
        a0 = fmaf(wf[c][4],x1.x,a0); a0 = fmaf(wf[c][5],x1.y,a0);
        a0 = fmaf(wf[c][6],x1.z,a0); a0 = fmaf(wf[c][7],x1.w,a0);
        a1 = fmaf(wf[c][0],y0.x,a1); a1 = fmaf(wf[c][1],y0.y,a1);
        a1 = fmaf(wf[c][2],y0.z,a1); a1 = fmaf(wf[c][3],y0.w,a1);
        a1 = fmaf(wf[c][4],y1.x,a1); a1 = fmaf(wf[c][5],y1.y,a1);
        a1 = fmaf(wf[c][6],y1.z,a1); a1 = fmaf(wf[c][7],y1.w,a1);
      }
    }

    // ---- publish partials + per-wave tag (no barrier) ----
    float* pp = pls[p];
    pp[      (wv * 65) + (kh << 5) + r] = a0;
    pp[520 + (wv * 65) + (kh << 5) + r] = a1;
    __asm__ volatile("s_waitcnt lgkmcnt(0)" ::: "memory");
    if (lane == 0) ptag[p][wv] = (u32)(t + 1);

    // ---- symmetric reduce: wave wv owns element e0+wv ----
    {
      volatile u32* tg = ptag[p];
      const u32 want = (u32)(t + 1);
      for (;;){
        bool ok = tg[0]==want && tg[1]==want && tg[2]==want && tg[3]==want &&
                  tg[4]==want && tg[5]==want && tg[6]==want && tg[7]==want;
        if (ok) break;
        __builtin_amdgcn_s_sleep(1);
      }
      __asm__ volatile("" ::: "memory");
    }
    const int b2 = lane >> 5;          // batch plane this lane reduces
    const int g2 = (lane >> 3) & 3;    // gate
    const int j2 = lane & 7;           // producer wave
    const int rd = b2 * 520 + j2 * 65 + (g2 << 3) + wv;
    float s = pls[p][rd] + pls[p][rd + 32];
    s += __shfl_xor(s, 1, 64);
    s += __shfl_xor(s, 2, 64);
    s += __shfl_xor(s, 4, 64);         // all 8 lanes of group hold (b2,g2) sum
    const int sb = (lane & 1) << 5;    // lane b gathers batch-b gates
    const float I = __shfl(s, sb,      64) + bg[0];
    const float F = __shfl(s, sb + 8,  64) + bg[1];
    const float G = __shfl(s, sb + 16, 64) + bg[2];
    const float O = __shfl(s, sb + 24, 64) + bg[3];
    const float cn = sigf(F) * c_reg + sigf(I) * tanhf(G);
    const float hn = sigf(O) * tanhf(cn);
    c_reg = cn;                        // garbage in lanes>=2 — never stored
    const float h1 = __shfl(hn, 1, 64);
    if (t < 2047 && lane == 0){
      const u32 pk = (u32)f2bf(hn) | ((u32)f2bf(h1) << 16);
      const u64 ch = ((u64)(u32)(t + 1) << 32) | (u64)pk;
      __hip_atomic_store(&chk[(((t + 1) & 1) << 11) + e0 + wv], ch,
                         __ATOMIC_RELAXED, __HIP_MEMORY_SCOPE_AGENT);
    }
    if (lane < 2)
      seqout[(((size_t)lane << 11) + (size_t)t) * E + e0 + wv] = hn;
  }
}

// In-place projection: out[row][n] = sum_k h[row][k]*Wout[n][k] + bout[n].
// Block owns 16 rows, staged to LDS first; 2 n-columns per pass.
__global__ void __launch_bounds__(256, 1) proj_kernel(
    float* __restrict__ io, const float* __restrict__ Wout,
    const float* __restrict__ bout)
{
  extern __shared__ char smem[];
  float* alds = (float*)smem;          // 16 x 2048 fp32 = 131072 B
  const int tid = threadIdx.x;
  const size_t rbase = (size_t)blockIdx.x * 16 * E;

  for (int idx = tid; idx < 8192; idx += 256){
    float4 v = *(const float4*)(io + rbase + ((size_t)idx << 2));
    *(float4*)(alds + (idx << 2)) = v;
  }
  __syncthreads();

  for (int p = 0; p < 4; ++p){
    const int n0 = (p << 8) + tid;
    const int n1 = n0 + 1024;
    const float* wr0 = Wout + (size_t)n0 * E;
    const float* wr1 = Wout + (size_t)n1 * E;
    float acc0[16], acc1[16];
    #pragma unroll
    for (int m = 0; m < 16; ++m){ acc0[m] = 0.0f; acc1[m] = 0.0f; }
    for (int kc = 0; kc < 256; ++kc){
      const float4 a0v = *(const float4*)(wr0 + (kc << 3));
      const float4 a1v = *(const float4*)(wr0 + (kc << 3) + 4);
      const float4 b0v = *(const float4*)(wr1 + (kc << 3));
      const float4 b1v = *(const float4*)(wr1 + (kc << 3) + 4);
      const float* ap = alds + (kc << 3);
      #pragma unroll
      for (int m = 0; m < 16; ++m){
        const float* a = ap + (m << 11);
        float4 x0 = *(const float4*)(a);
        float4 x1 = *(const float4*)(a + 4);
        acc0[m] = fmaf(a0v.x, x0.x, acc0[m]); acc0[m] = fmaf(a0v.y, x0.y, acc0[m]);
        acc0[m] = fmaf(a0v.z, x0.z, acc0[m]); acc0[m] = fmaf(a0v.w, x0.w, acc0[m]);
        acc0[m] = fmaf(a1v.x, x1.x, acc0[m]); acc0[m] = fmaf(a1v.y, x1.y, acc0[m]);
        acc0[m] = fmaf(a1v.z, x1.z, acc0[m]); acc0[m] = fmaf(a1v.w, x1.w, acc0[m]);
        acc1[m] = fmaf(b0v.x, x0.x, acc1[m]); acc1[m] = fmaf(b0v.y, x0.y, acc1[m]);
        acc1[m] = fmaf(b0v.z, x0.z, acc1[m]); acc1[m] = fmaf(b0v.w, x0.w, acc1[m]);
        acc1[m] = fmaf(b1v.x, x1.x, acc1[m]); acc1[m] = fmaf(b1v.y, x1.y, acc1[m]);
        acc1[m] = fmaf(b1v.z, x1.z, acc1[m]); acc1[m] = fmaf(b1v.w, x1.w, acc1[m]);
      }
    }
    const float bo0 = bout[n0];
    const float bo1 = bout[n1];
    #pragma unroll
    for (int m = 0; m < 16; ++m){
      io[rbase + ((size_t)m << 11) + n0] = acc0[m] + bo0;
      io[rbase + ((size_t)m << 11) + n1] = acc1[m] + bo1;
    }
  }
}

extern "C" void kernel_launch(void* const* d_in, const int* in_sizes, int n_in,
                              void* d_out, int out_size, void* d_ws, size_t ws_size,
                              hipStream_t stream)
{
  const float* xin  = (const float*)d_in[0];
  const float* Wih  = (const float*)d_in[1];
  const float* Whh  = (const float*)d_in[2];
  const float* bih  = (const float*)d_in[3];
  const float* bhh  = (const float*)d_in[4];
  const float* Wout = (const float*)d_in[5];
  const float* bout = (const float*)d_in[6];
  float* out = (float*)d_out;

  // chunk buffer: 2 parities x 2048 chunks x 8 B = 32 KB.
  // Poison 0xAAAAAAAA is never a valid tag (tags are 1..2047) -> no init pass.
  u64* chk = (u64*)d_ws;

  hipFuncSetAttribute((const void*)proj_kernel,
                      hipFuncAttributeMaxDynamicSharedMemorySize, SMEM_PROJ);

  void* args[] = { (void*)&xin, (void*)&Wih, (void*)&Whh, (void*)&bih, (void*)&bhh,
                   (void*)&chk, (void*)&out };
  hipLaunchCooperativeKernel((const void*)lstm_kernel, dim3(NBLK), dim3(NTHR),
                             args, 0, stream);

  proj_kernel<<<256, 256, SMEM_PROJ, stream>>>(out, Wout, bout);
}

// Round 5
// 34040.521 us; speedup vs baseline: 1.0001x; 1.0001x over previous
//
#include <hip/hip_runtime.h>
#include <stdint.h>

// LSTM, E=2048, B=2, T=2048, fp32 I/O. For t>=1 input==h, so
// gates = h @ (W_ih+W_hh)^T + (b_ih+b_hh). Wc lives UNPACKED FP32 IN
// REGISTERS: each lane holds its 128 weights in 128 VGPRs (no LDS weight
// traffic, no unpack VALU). 256 blocks (1/CU) x 512 threads, cooperative
// for co-residency only — ZERO barriers in the steady-state loop:
//  - each wave polls only its own 256-elem k-window from the global
//    tagged-chunk buffer (2048 chunks, [tag32|bf16 h0|bf16 h1]),
//  - stages h into its private hlds window (wave-lockstep + lgkmcnt),
//  - computes partials, publishes to LDS pls + per-wave LDS tag,
//  - every wave reduces its OWN element (wave w -> element e0+w) via
//    8-lane groups + shfl, keeps c in lane registers, fires its chunk.
// pls/ptag parity-double-buffered; chunk reuse is depth-2 safe because
// every block consumes ALL elements each step (transitive guarantee).
// __launch_bounds__(512,1): 256-VGPR cap -> wf stays in registers.
// (512,2) capped at 128 VGPR and spilled wf to scratch: 40 GB of HBM
// traffic, 3x regression (round-4 lesson).

#define E 2048
#define NBLK 256
#define NTHR 512
#define SMEM_PROJ 131072

typedef unsigned short u16;
typedef uint32_t u32;
typedef unsigned long long u64;

__device__ __forceinline__ float lo16(u32 u){ return __uint_as_float(u << 16); }
__device__ __forceinline__ float hi16(u32 u){ return __uint_as_float(u & 0xffff0000u); }
__device__ __forceinline__ u16 f2bf(float f){
  u32 u = __float_as_uint(f);
  u32 r = u + 0x7fffu + ((u >> 16) & 1u);   // RNE
  return (u16)(r >> 16);
}
__device__ __forceinline__ float sigf(float x){ return 1.0f / (1.0f + __expf(-x)); }

__global__ void __launch_bounds__(NTHR, 1) lstm_kernel(
    const float* __restrict__ xin, const float* __restrict__ Wih,
    const float* __restrict__ Whh, const float* __restrict__ bih,
    const float* __restrict__ bhh, u64* __restrict__ chk,
    float* __restrict__ seqout)
{
  __shared__ float hlds[2 * E];        // h (or x) fp32 [2][2048] = 16 KB
  __shared__ float pls[2][1040];       // [parity][b*520 + wv*65 + kh*32 + row]
  __shared__ u32  ptag[2][8];          // per-wave partial tags

  const int tid  = threadIdx.x;
  const int blk  = blockIdx.x;
  const int e0   = blk << 3;           // block owns elements e0..e0+7
  const int lane = tid & 63;
  const int wv   = tid >> 6;           // wave 0..7; wave wv reduces element e0+wv
  const int r    = lane & 31;          // row within block (gate*8 + eoff)
  const int kh   = lane >> 5;          // k-half
  const int kbase = (wv << 8) + (kh << 7);          // 128-wide k window
  const int grow_r = ((r >> 3) << 11) + e0 + (r & 7);

  // ---- Wc into registers: wf[c][j] = (Wih+Whh)[grow_r][kbase + c*8 + j]
  float wf[16][8];
  {
    const float* pa = Wih + (size_t)grow_r * E + kbase;
    const float* pb = Whh + (size_t)grow_r * E + kbase;
    #pragma unroll
    for (int c = 0; c < 16; ++c){
      float4 a0 = *(const float4*)(pa + (c << 3));
      float4 a1 = *(const float4*)(pa + (c << 3) + 4);
      float4 b0 = *(const float4*)(pb + (c << 3));
      float4 b1 = *(const float4*)(pb + (c << 3) + 4);
      wf[c][0] = a0.x + b0.x; wf[c][1] = a0.y + b0.y;
      wf[c][2] = a0.z + b0.z; wf[c][3] = a0.w + b0.w;
      wf[c][4] = a1.x + b1.x; wf[c][5] = a1.y + b1.y;
      wf[c][6] = a1.z + b1.z; wf[c][7] = a1.w + b1.w;
    }
  }
  float bg[4];
  #pragma unroll
  for (int g = 0; g < 4; ++g)
    bg[g] = bih[(g << 11) + e0 + wv] + bhh[(g << 11) + e0 + wv];

  float c_reg = 0.0f;                  // real c in lanes 0,1 only

  for (int i = tid; i < 2 * E; i += NTHR) hlds[i] = xin[i];   // x for t=0
  if (tid < 16) ((u32*)ptag)[tid] = 0;
  __syncthreads();                     // the ONLY block barrier

  const int ebase = kbase + (r << 2);  // this lane stages elements ebase..+3

  for (int t = 0; t < 2048; ++t){
    const int p = t & 1;

    // ---- poll own window's h(t) chunks, stage to private hlds window ----
    if (t > 0){
      const u64* src = chk + (p << 11);
      const u32 want = (u32)t;
      u64 uu[4];
      #pragma unroll
      for (int k = 0; k < 4; ++k)
        uu[k] = __hip_atomic_load(&src[ebase + k],
                                  __ATOMIC_RELAXED, __HIP_MEMORY_SCOPE_AGENT);
      for (;;){
        bool ok = ((u32)(uu[0] >> 32) == want) && ((u32)(uu[1] >> 32) == want) &&
                  ((u32)(uu[2] >> 32) == want) && ((u32)(uu[3] >> 32) == want);
        if (ok) break;
        __builtin_amdgcn_s_sleep(1);
        #pragma unroll
        for (int k = 0; k < 4; ++k)
          if ((u32)(uu[k] >> 32) != want)
            uu[k] = __hip_atomic_load(&src[ebase + k],
                                      __ATOMIC_RELAXED, __HIP_MEMORY_SCOPE_AGENT);
      }
      float4 v0 = { lo16((u32)uu[0]), lo16((u32)uu[1]),
                    lo16((u32)uu[2]), lo16((u32)uu[3]) };
      float4 v1 = { hi16((u32)uu[0]), hi16((u32)uu[1]),
                    hi16((u32)uu[2]), hi16((u32)uu[3]) };
      *(float4*)(&hlds[ebase])     = v0;
      *(float4*)(&hlds[E + ebase]) = v1;
      __asm__ volatile("s_waitcnt lgkmcnt(0)" ::: "memory");  // wave-internal
    }

    // ---- partial dot: row grow_r over k window [kbase, kbase+128) ----
    float a0 = 0.0f, a1 = 0.0f;
    const float* hp0 = &hlds[kbase];
    const float* hp1 = &hlds[E + kbase];
    if (t == 0){                       // x @ W_ih^T, fp32 weights from global
      const float* ws = Wih + (size_t)grow_r * E + kbase;
      #pragma unroll
      for (int c = 0; c < 16; ++c){
        float4 w0 = *(const float4*)(ws + (c << 3));
        float4 w1 = *(const float4*)(ws + (c << 3) + 4);
        float4 x0 = *(const float4*)(hp0 + (c << 3));
        float4 x1 = *(const float4*)(hp0 + (c << 3) + 4);
        float4 y0 = *(const float4*)(hp1 + (c << 3));
        float4 y1 = *(const float4*)(hp1 + (c << 3) + 4);
        a0 = fmaf(w0.x,x0.x,a0); a0 = fmaf(w0.y,x0.y,a0);
        a0 = fmaf(w0.z,x0.z,a0); a0 = fmaf(w0.w,x0.w,a0);
        a0 = fmaf(w1.x,x1.x,a0); a0 = fmaf(w1.y,x1.y,a0);
        a0 = fmaf(w1.z,x1.z,a0); a0 = fmaf(w1.w,x1.w,a0);
        a1 = fmaf(w0.x,y0.x,a1); a1 = fmaf(w0.y,y0.y,a1);
        a1 = fmaf(w0.z,y0.z,a1); a1 = fmaf(w0.w,y0.w,a1);
        a1 = fmaf(w1.x,y1.x,a1); a1 = fmaf(w1.y,y1.y,a1);
        a1 = fmaf(w1.z,y1.z,a1); a1 = fmaf(w1.w,y1.w,a1);
      }
    } else {                           // h @ Wc^T, weights from registers
      #pragma unroll
      for (int c = 0; c < 16; ++c){
        float4 x0 = *(const float4*)(hp0 + (c << 3));
        float4 x1 = *(const float4*)(hp0 + (c << 3) + 4);
        float4 y0 = *(const float4*)(hp1 + (c << 3));
        float4 y1 = *(const float4*)(hp1 + (c << 3) + 4);
        a0 = fmaf(wf[c][0],x0.x,a0); a0 = fmaf(wf[c][1],x0.y,a0);
        a0 = fmaf(wf[c][2],x0.z,a0); a0 = fmaf(wf[c][3],x0.w,a0);
        a0 = fmaf(wf[c][4],x1.x,a0); a0 = fmaf(wf[c][5],x1.y,a0);
        a0 = fmaf(wf[c][6],x1.z,a0); a0 = fmaf(wf[c][7],x1.w,a0);
        a1 = fmaf(wf[c][0],y0.x,a1); a1 = fmaf(wf[c][1],y0.y,a1);
        a1 = fmaf(wf[c][2],y0.z,a1); a1 = fmaf(wf[c][3],y0.w,a1);
        a1 = fmaf(wf[c][4],y1.x,a1); a1 = fmaf(wf[c][5],y1.y,a1);
        a1 = fmaf(wf[c][6],y1.z,a1); a1 = fmaf(wf[c][7],y1.w,a1);
      }
    }

    // ---- publish partials + per-wave tag (no barrier) ----
    float* pp = pls[p];
    pp[      (wv * 65) + (kh << 5) + r] = a0;
    pp[520 + (wv * 65) + (kh << 5) + r] = a1;
    __asm__ volatile("s_waitcnt lgkmcnt(0)" ::: "memory");
    if (lane == 0) ptag[p][wv] = (u32)(t + 1);

    // ---- symmetric reduce: wave wv owns element e0+wv ----
    {
      volatile u32* tg = ptag[p];
      const u32 want = (u32)(t + 1);
      for (;;){
        bool ok = tg[0]==want && tg[1]==want && tg[2]==want && tg[3]==want &&
                  tg[4]==want && tg[5]==want && tg[6]==want && tg[7]==want;
        if (ok) break;
        __builtin_amdgcn_s_sleep(1);
      }
      __asm__ volatile("" ::: "memory");
    }
    const int b2 = lane >> 5;          // batch plane this lane reduces
    const int g2 = (lane >> 3) & 3;    // gate
    const int j2 = lane & 7;           // producer wave
    const int rd = b2 * 520 + j2 * 65 + (g2 << 3) + wv;
    float s = pls[p][rd] + pls[p][rd + 32];
    s += __shfl_xor(s, 1, 64);
    s += __shfl_xor(s, 2, 64);
    s += __shfl_xor(s, 4, 64);         // all 8 lanes of group hold (b2,g2) sum
    const int sb = (lane & 1) << 5;    // lane b gathers batch-b gates
    const float I = __shfl(s, sb,      64) + bg[0];
    const float F = __shfl(s, sb + 8,  64) + bg[1];
    const float G = __shfl(s, sb + 16, 64) + bg[2];
    const float O = __shfl(s, sb + 24, 64) + bg[3];
    const float cn = sigf(F) * c_reg + sigf(I) * tanhf(G);
    const float hn = sigf(O) * tanhf(cn);
    c_reg = cn;                        // garbage in lanes>=2 — never stored
    const float h1 = __shfl(hn, 1, 64);
    if (t < 2047 && lane == 0){
      const u32 pk = (u32)f2bf(hn) | ((u32)f2bf(h1) << 16);
      const u64 ch = ((u64)(u32)(t + 1) << 32) | (u64)pk;
      __hip_atomic_store(&chk[(((t + 1) & 1) << 11) + e0 + wv], ch,
                         __ATOMIC_RELAXED, __HIP_MEMORY_SCOPE_AGENT);
    }
    if (lane < 2)
      seqout[(((size_t)lane << 11) + (size_t)t) * E + e0 + wv] = hn;
  }
}

// In-place projection: out[row][n] = sum_k h[row][k]*Wout[n][k] + bout[n].
// Block owns 16 rows, staged to LDS first; 2 n-columns per pass.
__global__ void __launch_bounds__(256, 1) proj_kernel(
    float* __restrict__ io, const float* __restrict__ Wout,
    const float* __restrict__ bout)
{
  extern __shared__ char smem[];
  float* alds = (float*)smem;          // 16 x 2048 fp32 = 131072 B
  const int tid = threadIdx.x;
  const size_t rbase = (size_t)blockIdx.x * 16 * E;

  for (int idx = tid; idx < 8192; idx += 256){
    float4 v = *(const float4*)(io + rbase + ((size_t)idx << 2));
    *(float4*)(alds + (idx << 2)) = v;
  }
  __syncthreads();

  for (int p = 0; p < 4; ++p){
    const int n0 = (p << 8) + tid;
    const int n1 = n0 + 1024;
    const float* wr0 = Wout + (size_t)n0 * E;
    const float* wr1 = Wout + (size_t)n1 * E;
    float acc0[16], acc1[16];
    #pragma unroll
    for (int m = 0; m < 16; ++m){ acc0[m] = 0.0f; acc1[m] = 0.0f; }
    for (int kc = 0; kc < 256; ++kc){
      const float4 a0v = *(const float4*)(wr0 + (kc << 3));
      const float4 a1v = *(const float4*)(wr0 + (kc << 3) + 4);
      const float4 b0v = *(const float4*)(wr1 + (kc << 3));
      const float4 b1v = *(const float4*)(wr1 + (kc << 3) + 4);
      const float* ap = alds + (kc << 3);
      #pragma unroll
      for (int m = 0; m < 16; ++m){
        const float* a = ap + (m << 11);
        float4 x0 = *(const float4*)(a);
        float4 x1 = *(const float4*)(a + 4);
        acc0[m] = fmaf(a0v.x, x0.x, acc0[m]); acc0[m] = fmaf(a0v.y, x0.y, acc0[m]);
        acc0[m] = fmaf(a0v.z, x0.z, acc0[m]); acc0[m] = fmaf(a0v.w, x0.w, acc0[m]);
        acc0[m] = fmaf(a1v.x, x1.x, acc0[m]); acc0[m] = fmaf(a1v.y, x1.y, acc0[m]);
        acc0[m] = fmaf(a1v.z, x1.z, acc0[m]); acc0[m] = fmaf(a1v.w, x1.w, acc0[m]);
        acc1[m] = fmaf(b0v.x, x0.x, acc1[m]); acc1[m] = fmaf(b0v.y, x0.y, acc1[m]);
        acc1[m] = fmaf(b0v.z, x0.z, acc1[m]); acc1[m] = fmaf(b0v.w, x0.w, acc1[m]);
        acc1[m] = fmaf(b1v.x, x1.x, acc1[m]); acc1[m] = fmaf(b1v.y, x1.y, acc1[m]);
        acc1[m] = fmaf(b1v.z, x1.z, acc1[m]); acc1[m] = fmaf(b1v.w, x1.w, acc1[m]);
      }
    }
    const float bo0 = bout[n0];
    const float bo1 = bout[n1];
    #pragma unroll
    for (int m = 0; m < 16; ++m){
      io[rbase + ((size_t)m << 11) + n0] = acc0[m] + bo0;
      io[rbase + ((size_t)m << 11) + n1] = acc1[m] + bo1;
    }
  }
}

extern "C" void kernel_launch(void* const* d_in, const int* in_sizes, int n_in,
                              void* d_out, int out_size, void* d_ws, size_t ws_size,
                              hipStream_t stream)
{
  const float* xin  = (const float*)d_in[0];
  const float* Wih  = (const float*)d_in[1];
  const float* Whh  = (const float*)d_in[2];
  const float* bih  = (const float*)d_in[3];
  const float* bhh  = (const float*)d_in[4];
  const float* Wout = (const float*)d_in[5];
  const float* bout = (const float*)d_in[6];
  float* out = (float*)d_out;

  // chunk buffer: 2 parities x 2048 chunks x 8 B = 32 KB.
  // Poison 0xAAAAAAAA is never a valid tag (tags are 1..2047) -> no init pass.
  u64* chk = (u64*)d_ws;

  hipFuncSetAttribute((const void*)proj_kernel,
                      hipFuncAttributeMaxDynamicSharedMemorySize, SMEM_PROJ);

  void* args[] = { (void*)&xin, (void*)&Wih, (void*)&Whh, (void*)&bih, (void*)&bhh,
                   (void*)&chk, (void*)&out };
  hipLaunchCooperativeKernel((const void*)lstm_kernel, dim3(NBLK), dim3(NTHR),
                             args, 0, stream);

  proj_kernel<<<256, 256, SMEM_PROJ, stream>>>(out, Wout, bout);
}